// Round 1
// baseline (863.906 us; speedup 1.0000x reference)
//
#include <hip/hip_runtime.h>
#include <math.h>

// ---------------------------------------------------------------------------
// SpanConsistencyNetwork — MI355X (gfx950)
// Pipeline: h->bf16; W1,W2 -> B^T bf16; per-m: MFMA GEMM1(+GELU) -> t1,
// GEMM2(+GELU) -> t2, scores dot; span-consistency; cross-marker MLP.
// Workspace layout (bytes):
//   hb   [32768][1024] bf16 @ 0          (67,108,864)
//   W1t  [5][512][1024] bf16 @ 67108864  ( 5,242,880)
//   W2t  [5][256][512]  bf16 @ 72351744  ( 1,310,720)
//   t1   [32768][512]   bf16 @ 73662464  (33,554,432)  (per-m reuse)
//   t2   [32768][256]   bf16 @ 107216896 (16,777,216)  (per-m reuse)
//   scr  [5][16][2048]  f32  @ 123994112 (   655,360)
//   lgt  [16][2048][5]  f32  @ 124649472 (   655,360)
// total ~125.3 MB
// ---------------------------------------------------------------------------

typedef __bf16 bf16x8 __attribute__((ext_vector_type(8)));
typedef float f32x4 __attribute__((ext_vector_type(4)));

#define NEG_INF_VAL (-10000.0f)

__device__ __forceinline__ unsigned short f2bf(float f) {
  union { float f; unsigned u; } v; v.f = f;
  unsigned r = v.u + 0x7fffu + ((v.u >> 16) & 1u);   // RNE
  return (unsigned short)(r >> 16);
}
__device__ __forceinline__ float bf2f(unsigned short b) {
  union { unsigned u; float f; } v; v.u = ((unsigned)b) << 16;
  return v.f;
}
__device__ __forceinline__ float gelu_erf(float x) {
  return 0.5f * x * (1.0f + erff(x * 0.7071067811865476f));
}

// ---- h fp32 -> bf16 (vectorized) ----
__global__ __launch_bounds__(256) void k_f32_to_bf16x4(
    const float* __restrict__ in, unsigned short* __restrict__ out, int n4) {
  int i = blockIdx.x * 256 + threadIdx.x;
  if (i >= n4) return;
  float4 v = reinterpret_cast<const float4*>(in)[i];
  ushort4 o;
  o.x = f2bf(v.x); o.y = f2bf(v.y); o.z = f2bf(v.z); o.w = f2bf(v.w);
  reinterpret_cast<ushort4*>(out)[i] = o;
}

// ---- W [M][K][C] f32 -> Wt [M][C][K] bf16 ----
__global__ __launch_bounds__(256) void k_transpose_bf16(
    const float* __restrict__ W, unsigned short* __restrict__ Wt,
    int K, int C, int total) {
  int i = blockIdx.x * 256 + threadIdx.x;
  if (i >= total) return;
  int per = K * C;
  int m = i / per;
  int rem = i - m * per;
  int c = rem / K;
  int k = rem - c * K;
  Wt[i] = f2bf(W[(size_t)m * per + (size_t)k * C + c]);
}

// ---- bf16 GEMM (B^T input) + bias + erf-GELU, bf16 out. m97-style 128x128 ----
#define BM 128
#define BN 128
#define BKK 32

__global__ __launch_bounds__(256) void k_gemm_gelu(
    const unsigned short* __restrict__ A,   // [Mrows][K] bf16
    const unsigned short* __restrict__ Bt,  // [N][K]     bf16
    const float* __restrict__ bias,         // [N]
    unsigned short* __restrict__ C,         // [Mrows][N] bf16
    int K, int N) {
  __shared__ unsigned short As[BM * BKK];
  __shared__ unsigned short Bs[BN * BKK];
  const int t = threadIdx.x;
  const int lane = t & 63;
  const int w = t >> 6;
  const int wr = w >> 1, wc = w & 1;
  const int row0 = blockIdx.y * BM;
  const int col0 = blockIdx.x * BN;

  f32x4 acc[4][4];
#pragma unroll
  for (int i = 0; i < 4; i++)
#pragma unroll
    for (int j = 0; j < 4; j++)
      acc[i][j] = (f32x4){0.f, 0.f, 0.f, 0.f};

  const int sr = t >> 2;           // staging row within 64-row chunk
  const int sk = (t & 3) * 8;      // staging k offset (elements)

  for (int kt = 0; kt < K; kt += BKK) {
#pragma unroll
    for (int c2 = 0; c2 < 2; c2++) {
      const unsigned short* ga = &A[(size_t)(row0 + c2 * 64 + sr) * K + kt + sk];
      __builtin_amdgcn_global_load_lds(
          (const __attribute__((address_space(1))) void*)ga,
          (__attribute__((address_space(3))) void*)&As[(c2 * 64 + sr) * BKK + sk],
          16, 0, 0);
      const unsigned short* gb = &Bt[(size_t)(col0 + c2 * 64 + sr) * K + kt + sk];
      __builtin_amdgcn_global_load_lds(
          (const __attribute__((address_space(1))) void*)gb,
          (__attribute__((address_space(3))) void*)&Bs[(c2 * 64 + sr) * BKK + sk],
          16, 0, 0);
    }
    __syncthreads();
    const int kq = (lane >> 4) * 8;
    const int r16 = lane & 15;
    bf16x8 af[4], bfr[4];
#pragma unroll
    for (int i = 0; i < 4; i++)
      af[i] = *reinterpret_cast<const bf16x8*>(&As[(wr * 64 + i * 16 + r16) * BKK + kq]);
#pragma unroll
    for (int j = 0; j < 4; j++)
      bfr[j] = *reinterpret_cast<const bf16x8*>(&Bs[(wc * 64 + j * 16 + r16) * BKK + kq]);
#pragma unroll
    for (int i = 0; i < 4; i++)
#pragma unroll
      for (int j = 0; j < 4; j++)
        acc[i][j] = __builtin_amdgcn_mfma_f32_16x16x32_bf16(af[i], bfr[j], acc[i][j], 0, 0, 0);
    __syncthreads();
  }

  const int orow = (lane >> 4) * 4;
  const int ocol = lane & 15;
#pragma unroll
  for (int i = 0; i < 4; i++) {
#pragma unroll
    for (int j = 0; j < 4; j++) {
      int gcol = col0 + wc * 64 + j * 16 + ocol;
      float b = bias[gcol];
#pragma unroll
      for (int r = 0; r < 4; r++) {
        int grow = row0 + wr * 64 + i * 16 + orow + r;
        float v = acc[i][j][r] + b;
        v = gelu_erf(v);
        C[(size_t)grow * N + gcol] = f2bf(v);
      }
    }
  }
}

// ---- scores: wave-per-row 256-dot with W3[m], +b3[m] ----
__global__ __launch_bounds__(256) void k_scores(
    const unsigned short* __restrict__ t2,  // [32768][256] bf16 (current m)
    const float* __restrict__ W3,           // [5][256]
    const float* __restrict__ b3,           // [5]
    float* __restrict__ scores,             // [5][32768]
    int m) {
  __shared__ float w3s[256];
  w3s[threadIdx.x] = W3[m * 256 + threadIdx.x];
  __syncthreads();
  int wid = threadIdx.x >> 6, lane = threadIdx.x & 63;
  int r = blockIdx.x * 4 + wid;
  const unsigned short* row = t2 + (size_t)r * 256;
  ushort4 v = reinterpret_cast<const ushort4*>(row)[lane];
  float s = bf2f(v.x) * w3s[lane * 4 + 0] + bf2f(v.y) * w3s[lane * 4 + 1] +
            bf2f(v.z) * w3s[lane * 4 + 2] + bf2f(v.w) * w3s[lane * 4 + 3];
#pragma unroll
  for (int off = 32; off > 0; off >>= 1) s += __shfl_down(s, off);
  if (lane == 0) scores[m * 32768 + r] = s + b3[m];
}

// ---- span consistency: block per (b, m) ----
__global__ __launch_bounds__(256) void k_span(
    const float* __restrict__ scores,   // [5][16][2048]
    const int* __restrict__ mask,       // [16][2048]
    const float* __restrict__ gamma,    // [5]
    const float* __restrict__ wlog,     // [5][15]
    float* __restrict__ logits) {       // [16][2048][5]
  const int b = blockIdx.x, m = blockIdx.y;
  const int tid = threadIdx.x;
  __shared__ float masked[2048], mins[2048], boost[2048];
  __shared__ float ww[14];
  if (tid == 0) {
    float mx = -1e30f;
    for (int i = 0; i < 15; i++) mx = fmaxf(mx, wlog[m * 15 + i]);
    float e[15], sum = 0.f;
    for (int i = 0; i < 15; i++) { e[i] = expf(wlog[m * 15 + i] - mx); sum += e[i]; }
    for (int i = 0; i < 14; i++) ww[i] = e[i] / sum;   // index 14 unused (w<=15)
  }
  const float* srow = scores + ((size_t)m * 16 + b) * 2048;
  const int* mrow = mask + (size_t)b * 2048;
  for (int i = tid; i < 2048; i += 256) {
    float s = srow[i];
    float mk = (mrow[i] == 0) ? NEG_INF_VAL : s;
    masked[i] = mk; mins[i] = mk; boost[i] = mk;
  }
  __syncthreads();
  for (int w2 = 2; w2 <= 15; w2++) {
    // widen sliding-window min incrementally: width (w2-1) -> w2
    for (int s = tid; s <= 2048 - w2; s += 256)
      mins[s] = fminf(mins[s], masked[s + w2 - 1]);
    __syncthreads();
    float c = ww[w2 - 2];
    for (int i = tid; i < 2048; i += 256) {
      int lo = i - w2 + 1; if (lo < 0) lo = 0;
      int hi = i; if (hi > 2048 - w2) hi = 2048 - w2;
      float mx = -1e30f;
      for (int s = lo; s <= hi; s++) mx = fmaxf(mx, mins[s]);
      boost[i] = fmaxf(boost[i], mx * c);   // c>0 so max(c*x)=c*max(x)
    }
    __syncthreads();
  }
  float g = gamma[m];
  for (int i = tid; i < 2048; i += 256)
    logits[((size_t)b * 2048 + i) * 5 + m] = srow[i] + g * boost[i];
}

// ---- cross-marker refinement: thread per token ----
__global__ __launch_bounds__(256) void k_cross(
    const float* __restrict__ logits,  // [B*N][5]
    const float* __restrict__ corr,    // [5][5]
    const float* __restrict__ cw1,     // [5][64]
    const float* __restrict__ cb1,     // [64]
    const float* __restrict__ cw2,     // [64][5]
    const float* __restrict__ cb2,     // [5]
    const float* __restrict__ gate,    // [1]
    float* __restrict__ out) {         // [B*N][5]
  __shared__ float s_corr[25], s_cw1[320], s_cb1[64], s_cw2[320], s_cb2[5];
  int tid = threadIdx.x;
  if (tid < 25) s_corr[tid] = corr[tid];
  if (tid < 64) s_cb1[tid] = cb1[tid];
  if (tid < 5)  s_cb2[tid] = cb2[tid];
  for (int i = tid; i < 320; i += 256) { s_cw1[i] = cw1[i]; s_cw2[i] = cw2[i]; }
  __syncthreads();
  int t = blockIdx.x * 256 + tid;
  float lg[5], pr[5];
#pragma unroll
  for (int m = 0; m < 5; m++) {
    lg[m] = logits[(size_t)t * 5 + m];
    pr[m] = 1.f / (1.f + expf(-lg[m]));
  }
  float co[5];
#pragma unroll
  for (int j = 0; j < 5; j++) {
    float s = 0.f;
#pragma unroll
    for (int mm = 0; mm < 5; mm++) s += pr[mm] * s_corr[mm * 5 + j];
    co[j] = s;
  }
  float ref[5];
#pragma unroll
  for (int m = 0; m < 5; m++) ref[m] = s_cb2[m];
  for (int k = 0; k < 64; k++) {
    float h = s_cb1[k];
#pragma unroll
    for (int j = 0; j < 5; j++) h += co[j] * s_cw1[j * 64 + k];
    h = gelu_erf(h);
#pragma unroll
    for (int m = 0; m < 5; m++) ref[m] += h * s_cw2[k * 5 + m];
  }
  float sg = 1.f / (1.f + expf(-gate[0]));
#pragma unroll
  for (int m = 0; m < 5; m++) out[(size_t)t * 5 + m] = lg[m] + sg * ref[m];
}

extern "C" void kernel_launch(void* const* d_in, const int* in_sizes, int n_in,
                              void* d_out, int out_size, void* d_ws, size_t ws_size,
                              hipStream_t stream) {
  const float* h     = (const float*)d_in[0];
  const int*   mask  = (const int*)d_in[1];
  const float* W1    = (const float*)d_in[2];
  const float* b1    = (const float*)d_in[3];
  const float* W2    = (const float*)d_in[4];
  const float* b2    = (const float*)d_in[5];
  const float* W3    = (const float*)d_in[6];
  const float* b3    = (const float*)d_in[7];
  const float* gamma = (const float*)d_in[8];
  const float* wlog  = (const float*)d_in[9];
  const float* corr  = (const float*)d_in[10];
  const float* cw1   = (const float*)d_in[11];
  const float* cb1   = (const float*)d_in[12];
  const float* cw2   = (const float*)d_in[13];
  const float* cb2   = (const float*)d_in[14];
  const float* gate  = (const float*)d_in[15];
  float* out = (float*)d_out;

  char* ws = (char*)d_ws;
  unsigned short* hb  = (unsigned short*)(ws);
  unsigned short* W1t = (unsigned short*)(ws + 67108864);
  unsigned short* W2t = (unsigned short*)(ws + 72351744);
  unsigned short* t1  = (unsigned short*)(ws + 73662464);
  unsigned short* t2  = (unsigned short*)(ws + 107216896);
  float* scores       = (float*)(ws + 123994112);
  float* logits       = (float*)(ws + 124649472);

  // h -> bf16 (33,554,432 elems, 4/thread)
  k_f32_to_bf16x4<<<33554432 / 4 / 256, 256, 0, stream>>>(h, hb, 33554432 / 4);
  // W1 [5][1024][512] -> W1t [5][512][1024]
  k_transpose_bf16<<<(2621440 + 255) / 256, 256, 0, stream>>>(W1, W1t, 1024, 512, 2621440);
  // W2 [5][512][256] -> W2t [5][256][512]
  k_transpose_bf16<<<(655360 + 255) / 256, 256, 0, stream>>>(W2, W2t, 512, 256, 655360);

  for (int m = 0; m < 5; m++) {
    k_gemm_gelu<<<dim3(4, 256), 256, 0, stream>>>(
        hb, W1t + (size_t)m * 512 * 1024, b1 + m * 512, t1, 1024, 512);
    k_gemm_gelu<<<dim3(2, 256), 256, 0, stream>>>(
        t1, W2t + (size_t)m * 256 * 512, b2 + m * 256, t2, 512, 256);
    k_scores<<<8192, 256, 0, stream>>>(t2, W3, b3, scores, m);
  }
  k_span<<<dim3(16, 5), 256, 0, stream>>>(scores, mask, gamma, wlog, logits);
  k_cross<<<32768 / 256, 256, 0, stream>>>(logits, corr, cw1, cb1, cw2, cb2, gate, out);
}

// Round 2
// 858.195 us; speedup vs baseline: 1.0067x; 1.0067x over previous
//
#include <hip/hip_runtime.h>
#include <math.h>

// ---------------------------------------------------------------------------
// SpanConsistencyNetwork — MI355X (gfx950), round 2
// Changes vs R1: conflict-free kc-major LDS layout (granule pos = kc*16+row,
// realized by permuting the *global* source addr of global_load_lds; reads
// become base+lane*16), fast tanh-GELU epilogue, all-marker fused GEMMs with
// XCD swizzle, tiled coalesced weight transposes, batched scores.
// Fused ws layout (bytes):
//   hb   [32768][1024]  bf16 @ 0          (67,108,864)
//   W1t  [2560][1024]   bf16 @ 67108864   ( 5,242,880)
//   W2t  [1280][512]    bf16 @ 72351744   ( 1,310,720)
//   t1   [32768][2560]  bf16 @ 73662464   (167,772,160)
//   t2   [32768][1280]  bf16 @ 241434624  ( 83,886,080)
//   scr  [5][32768]     f32  @ 325320704  (    655,360)
//   lgt  [32768][5]     f32  @ 325976064  (    655,360)   total 326,631,424
// Fallback (ws < 327MB): R1's per-m layout (125MB).
// ---------------------------------------------------------------------------

typedef __bf16 bf16x8 __attribute__((ext_vector_type(8)));
typedef float f32x4 __attribute__((ext_vector_type(4)));

#define NEG_INF_VAL (-10000.0f)

__device__ __forceinline__ unsigned short f2bf(float f) {
  union { float f; unsigned u; } v; v.f = f;
  unsigned r = v.u + 0x7fffu + ((v.u >> 16) & 1u);   // RNE
  return (unsigned short)(r >> 16);
}
__device__ __forceinline__ float bf2f(unsigned short b) {
  union { unsigned u; float f; } v; v.u = ((unsigned)b) << 16;
  return v.f;
}
__device__ __forceinline__ float gelu_erf(float x) {
  return 0.5f * x * (1.0f + erff(x * 0.7071067811865476f));
}
// tanh-based GELU (max |dev| vs erf-GELU ~5e-4; attenuated downstream)
__device__ __forceinline__ float gelu_fast(float x) {
  float u = 0.7978845608f * x * (1.0f + 0.044715f * x * x);
  float e = __expf(-2.0f * fabsf(u));
  float t = (1.0f - e) / (1.0f + e);
  t = copysignf(t, u);
  return 0.5f * x * (1.0f + t);
}

// ---- h fp32 -> bf16 (vectorized) ----
__global__ __launch_bounds__(256) void k_f32_to_bf16x4(
    const float* __restrict__ in, unsigned short* __restrict__ out, int n4) {
  int i = blockIdx.x * 256 + threadIdx.x;
  if (i >= n4) return;
  float4 v = reinterpret_cast<const float4*>(in)[i];
  ushort4 o;
  o.x = f2bf(v.x); o.y = f2bf(v.y); o.z = f2bf(v.z); o.w = f2bf(v.w);
  reinterpret_cast<ushort4*>(out)[i] = o;
}

// ---- tiled transpose: W [M][K][C] f32 -> Wt [M][C][K] bf16 (coalesced) ----
__global__ __launch_bounds__(256) void k_transpose_tiled(
    const float* __restrict__ W, unsigned short* __restrict__ Wt,
    int K, int C) {
  __shared__ float tile[32][33];
  const int m = blockIdx.z;
  const int c0 = blockIdx.x * 32, k0 = blockIdx.y * 32;
  const int tx = threadIdx.x & 31, ty = threadIdx.x >> 5;  // ty: 0..7
  const float* Wm = W + (size_t)m * K * C;
#pragma unroll
  for (int r = ty; r < 32; r += 8)
    tile[r][tx] = Wm[(size_t)(k0 + r) * C + c0 + tx];
  __syncthreads();
  unsigned short* Wtm = Wt + (size_t)m * C * K;
#pragma unroll
  for (int r = ty; r < 32; r += 8)
    Wtm[(size_t)(c0 + r) * K + k0 + tx] = f2bf(tile[tx][r]);
}

// ---- bf16 GEMM (B^T) + bias + fast GELU, bf16 out. 128x128 tile, BK=32.
// LDS layout: [rowGroup(8)][kc(4)][rowLocal(16)][8 elems] — granule pos within
// each wave's 1KB = kc*16+rowLocal, so fragment reads are base+lane*16
// (conflict-free) and staging dest is linear (global src pre-permuted). ----
__global__ __launch_bounds__(256) void k_gemm_gelu(
    const unsigned short* __restrict__ A, int lda, int aOffPerM,
    const unsigned short* __restrict__ Bt,
    const float* __restrict__ bias,
    unsigned short* __restrict__ C, int ldc,
    int K, int tilesPerM, int colsPerM, int nColTiles) {
  __shared__ unsigned short As[4096];
  __shared__ unsigned short Bs[4096];
  const int t = threadIdx.x;
  const int lane = t & 63;
  const int w = t >> 6;
  const int wr = w >> 1, wc = w & 1;

  // bijective XCD swizzle (nwg % 8 == 0 for all our launches), col-fast
  const int nwg = gridDim.x;
  const int cpx = nwg >> 3;
  const int bid = blockIdx.x;
  const int swz = (bid & 7) * cpx + (bid >> 3);
  const int ct = swz % nColTiles;
  const int rt = swz / nColTiles;
  const int m = ct / tilesPerM;
  const int cb = ct - m * tilesPerM;
  const int gcol0 = m * colsPerM + cb * 128;
  const int row0 = rt * 128;

  const unsigned short* Am = A + (size_t)m * aOffPerM;

  f32x4 acc[4][4];
#pragma unroll
  for (int i = 0; i < 4; i++)
#pragma unroll
    for (int j = 0; j < 4; j++)
      acc[i][j] = (f32x4){0.f, 0.f, 0.f, 0.f};

  // staging: thread t supplies granule (row = (t>>6)*16 + (t&15), kc = (t>>4)&3)
  const int srow = ((t >> 6) << 4) + (t & 15);
  const int skc8 = ((t >> 4) & 3) * 8;

  for (int kt = 0; kt < K; kt += 32) {
#pragma unroll
    for (int c2 = 0; c2 < 2; c2++) {
      const unsigned short* ga = &Am[(size_t)(row0 + c2 * 64 + srow) * lda + kt + skc8];
      __builtin_amdgcn_global_load_lds(
          (const __attribute__((address_space(1))) void*)ga,
          (__attribute__((address_space(3))) void*)&As[c2 * 2048 + t * 8],
          16, 0, 0);
      const unsigned short* gb = &Bt[(size_t)(gcol0 + c2 * 64 + srow) * K + kt + skc8];
      __builtin_amdgcn_global_load_lds(
          (const __attribute__((address_space(1))) void*)gb,
          (__attribute__((address_space(3))) void*)&Bs[c2 * 2048 + t * 8],
          16, 0, 0);
    }
    __syncthreads();
    bf16x8 af[4], bfr[4];
#pragma unroll
    for (int i = 0; i < 4; i++)
      af[i] = *reinterpret_cast<const bf16x8*>(&As[(wr * 4 + i) * 512 + lane * 8]);
#pragma unroll
    for (int j = 0; j < 4; j++)
      bfr[j] = *reinterpret_cast<const bf16x8*>(&Bs[(wc * 4 + j) * 512 + lane * 8]);
#pragma unroll
    for (int i = 0; i < 4; i++)
#pragma unroll
      for (int j = 0; j < 4; j++)
        acc[i][j] = __builtin_amdgcn_mfma_f32_16x16x32_bf16(af[i], bfr[j], acc[i][j], 0, 0, 0);
    __syncthreads();
  }

  const int orow = (lane >> 4) * 4;
  const int ocol = lane & 15;
#pragma unroll
  for (int i = 0; i < 4; i++) {
#pragma unroll
    for (int j = 0; j < 4; j++) {
      int gcol = gcol0 + wc * 64 + j * 16 + ocol;
      float b = bias[gcol];
#pragma unroll
      for (int r = 0; r < 4; r++) {
        int grow = row0 + wr * 64 + i * 16 + orow + r;
        float v = acc[i][j][r] + b;
        v = gelu_fast(v);
        C[(size_t)grow * ldc + gcol] = f2bf(v);
      }
    }
  }
}

// ---- scores: wave-per-(row,m) 256-dot with W3[m], +b3[m] ----
__global__ __launch_bounds__(256) void k_scores(
    const unsigned short* __restrict__ t2,  // [32768][ld] bf16
    int ld, int colStride, int mBase,
    const float* __restrict__ W3,           // [5][256]
    const float* __restrict__ b3,           // [5]
    float* __restrict__ scores) {           // [5][32768]
  const int m = mBase + blockIdx.y;
  __shared__ float w3s[256];
  w3s[threadIdx.x] = W3[m * 256 + threadIdx.x];
  __syncthreads();
  int wid = threadIdx.x >> 6, lane = threadIdx.x & 63;
  int r = blockIdx.x * 4 + wid;
  const unsigned short* row = t2 + (size_t)r * ld + blockIdx.y * colStride;
  ushort4 v = reinterpret_cast<const ushort4*>(row)[lane];
  float s = bf2f(v.x) * w3s[lane * 4 + 0] + bf2f(v.y) * w3s[lane * 4 + 1] +
            bf2f(v.z) * w3s[lane * 4 + 2] + bf2f(v.w) * w3s[lane * 4 + 3];
#pragma unroll
  for (int off = 32; off > 0; off >>= 1) s += __shfl_down(s, off);
  if (lane == 0) scores[m * 32768 + r] = s + b3[m];
}

// ---- span consistency: block per (b, m) ----
__global__ __launch_bounds__(256) void k_span(
    const float* __restrict__ scores,   // [5][16][2048]
    const int* __restrict__ mask,       // [16][2048]
    const float* __restrict__ gamma,    // [5]
    const float* __restrict__ wlog,     // [5][15]
    float* __restrict__ logits) {       // [16][2048][5]
  const int b = blockIdx.x, m = blockIdx.y;
  const int tid = threadIdx.x;
  __shared__ float masked[2048], mins[2048], boost[2048];
  __shared__ float ww[14];
  if (tid == 0) {
    float mx = -1e30f;
    for (int i = 0; i < 15; i++) mx = fmaxf(mx, wlog[m * 15 + i]);
    float e[15], sum = 0.f;
    for (int i = 0; i < 15; i++) { e[i] = expf(wlog[m * 15 + i] - mx); sum += e[i]; }
    for (int i = 0; i < 14; i++) ww[i] = e[i] / sum;   // index 14 unused (w<=15)
  }
  const float* srow = scores + ((size_t)m * 16 + b) * 2048;
  const int* mrow = mask + (size_t)b * 2048;
  for (int i = tid; i < 2048; i += 256) {
    float s = srow[i];
    float mk = (mrow[i] == 0) ? NEG_INF_VAL : s;
    masked[i] = mk; mins[i] = mk; boost[i] = mk;
  }
  __syncthreads();
  for (int w2 = 2; w2 <= 15; w2++) {
    for (int s = tid; s <= 2048 - w2; s += 256)
      mins[s] = fminf(mins[s], masked[s + w2 - 1]);
    __syncthreads();
    float c = ww[w2 - 2];
    for (int i = tid; i < 2048; i += 256) {
      int lo = i - w2 + 1; if (lo < 0) lo = 0;
      int hi = i; if (hi > 2048 - w2) hi = 2048 - w2;
      float mx = -1e30f;
      for (int s = lo; s <= hi; s++) mx = fmaxf(mx, mins[s]);
      boost[i] = fmaxf(boost[i], mx * c);   // c>0 so max(c*x)=c*max(x)
    }
    __syncthreads();
  }
  float g = gamma[m];
  for (int i = tid; i < 2048; i += 256)
    logits[((size_t)b * 2048 + i) * 5 + m] = srow[i] + g * boost[i];
}

// ---- cross-marker refinement: thread per token ----
__global__ __launch_bounds__(256) void k_cross(
    const float* __restrict__ logits,  // [B*N][5]
    const float* __restrict__ corr,    // [5][5]
    const float* __restrict__ cw1,     // [5][64]
    const float* __restrict__ cb1,     // [64]
    const float* __restrict__ cw2,     // [64][5]
    const float* __restrict__ cb2,     // [5]
    const float* __restrict__ gate,    // [1]
    float* __restrict__ out) {         // [B*N][5]
  __shared__ float s_corr[25], s_cw1[320], s_cb1[64], s_cw2[320], s_cb2[5];
  int tid = threadIdx.x;
  if (tid < 25) s_corr[tid] = corr[tid];
  if (tid < 64) s_cb1[tid] = cb1[tid];
  if (tid < 5)  s_cb2[tid] = cb2[tid];
  for (int i = tid; i < 320; i += 256) { s_cw1[i] = cw1[i]; s_cw2[i] = cw2[i]; }
  __syncthreads();
  int t = blockIdx.x * 256 + tid;
  float lg[5], pr[5];
#pragma unroll
  for (int m = 0; m < 5; m++) {
    lg[m] = logits[(size_t)t * 5 + m];
    pr[m] = 1.f / (1.f + expf(-lg[m]));
  }
  float co[5];
#pragma unroll
  for (int j = 0; j < 5; j++) {
    float s = 0.f;
#pragma unroll
    for (int mm = 0; mm < 5; mm++) s += pr[mm] * s_corr[mm * 5 + j];
    co[j] = s;
  }
  float ref[5];
#pragma unroll
  for (int m = 0; m < 5; m++) ref[m] = s_cb2[m];
  for (int k = 0; k < 64; k++) {
    float h = s_cb1[k];
#pragma unroll
    for (int j = 0; j < 5; j++) h += co[j] * s_cw1[j * 64 + k];
    h = gelu_erf(h);
#pragma unroll
    for (int m = 0; m < 5; m++) ref[m] += h * s_cw2[k * 5 + m];
  }
  float sg = 1.f / (1.f + expf(-gate[0]));
#pragma unroll
  for (int m = 0; m < 5; m++) out[(size_t)t * 5 + m] = lg[m] + sg * ref[m];
}

extern "C" void kernel_launch(void* const* d_in, const int* in_sizes, int n_in,
                              void* d_out, int out_size, void* d_ws, size_t ws_size,
                              hipStream_t stream) {
  const float* h     = (const float*)d_in[0];
  const int*   mask  = (const int*)d_in[1];
  const float* W1    = (const float*)d_in[2];
  const float* b1    = (const float*)d_in[3];   // [5][512] = fused [2560]
  const float* W2    = (const float*)d_in[4];
  const float* b2    = (const float*)d_in[5];   // [5][256] = fused [1280]
  const float* W3    = (const float*)d_in[6];
  const float* b3    = (const float*)d_in[7];
  const float* gamma = (const float*)d_in[8];
  const float* wlog  = (const float*)d_in[9];
  const float* corr  = (const float*)d_in[10];
  const float* cw1   = (const float*)d_in[11];
  const float* cb1   = (const float*)d_in[12];
  const float* cw2   = (const float*)d_in[13];
  const float* cb2   = (const float*)d_in[14];
  const float* gate  = (const float*)d_in[15];
  float* out = (float*)d_out;

  char* ws = (char*)d_ws;
  const bool fused = ws_size >= 326631424ULL;

  unsigned short* hb  = (unsigned short*)(ws);
  unsigned short* W1t = (unsigned short*)(ws + 67108864);
  unsigned short* W2t = (unsigned short*)(ws + 72351744);

  // common prolog: h->bf16, weight transposes
  k_f32_to_bf16x4<<<33554432 / 4 / 256, 256, 0, stream>>>(h, hb, 33554432 / 4);
  k_transpose_tiled<<<dim3(16, 32, 5), 256, 0, stream>>>(W1, W1t, 1024, 512);
  k_transpose_tiled<<<dim3(8, 16, 5), 256, 0, stream>>>(W2, W2t, 512, 256);

  if (fused) {
    unsigned short* t1  = (unsigned short*)(ws + 73662464);
    unsigned short* t2  = (unsigned short*)(ws + 241434624);
    float* scores       = (float*)(ws + 325320704);
    float* logits       = (float*)(ws + 325976064);

    // GEMM1: [32768,1024] x [2560,1024]^T -> t1 [32768,2560]
    k_gemm_gelu<<<20 * 256, 256, 0, stream>>>(
        hb, 1024, 0, W1t, b1, t1, 2560, 1024, 20, 2560, 20);
    // GEMM2 batched over m: per m A = t1[:, m*512 +: 512], Bt rows m*256 +: 256
    k_gemm_gelu<<<10 * 256, 256, 0, stream>>>(
        t1, 2560, 512, W2t, b2, t2, 1280, 512, 2, 256, 10);
    // scores for all m
    k_scores<<<dim3(8192, 5), 256, 0, stream>>>(t2, 1280, 256, 0, W3, b3, scores);
    k_span<<<dim3(16, 5), 256, 0, stream>>>(scores, mask, gamma, wlog, logits);
    k_cross<<<32768 / 256, 256, 0, stream>>>(logits, corr, cw1, cb1, cw2, cb2, gate, out);
  } else {
    unsigned short* t1s = (unsigned short*)(ws + 73662464);   // [32768][512]
    unsigned short* t2s = (unsigned short*)(ws + 107216896);  // [32768][256]
    float* scores       = (float*)(ws + 123994112);
    float* logits       = (float*)(ws + 124649472);

    for (int m = 0; m < 5; m++) {
      k_gemm_gelu<<<4 * 256, 256, 0, stream>>>(
          hb, 1024, 0, W1t + (size_t)m * 512 * 1024, b1 + m * 512,
          t1s, 512, 1024, 4, 512, 4);
      k_gemm_gelu<<<2 * 256, 256, 0, stream>>>(
          t1s, 512, 0, W2t + (size_t)m * 256 * 512, b2 + m * 256,
          t2s, 256, 512, 2, 256, 2);
      k_scores<<<dim3(8192, 1), 256, 0, stream>>>(t2s, 256, 0, m, W3, b3, scores);
    }
    k_span<<<dim3(16, 5), 256, 0, stream>>>(scores, mask, gamma, wlog, logits);
    k_cross<<<32768 / 256, 256, 0, stream>>>(logits, corr, cw1, cb1, cw2, cb2, gate, out);
  }
}

// Round 3
// 679.629 us; speedup vs baseline: 1.2711x; 1.2627x over previous
//
#include <hip/hip_runtime.h>
#include <math.h>

// ---------------------------------------------------------------------------
// SpanConsistencyNetwork — MI355X (gfx950), round 3
// 256x256 tile, BK=64, 8 waves (2Mx4N), depth-2 counted-vmcnt pipeline:
//   per K-tile: ds_read 24 frags -> lgkmcnt(0) -> s_barrier -> issue
//   stage(t+2) into freed slot -> 64 MFMA (setprio) -> vmcnt(8) (tile t+1
//   landed; never drain to 0 mid-loop) -> s_barrier.
// GEMM2 fuses the scores dot (t2 never materialized).
// ws layout (bytes):
//   hb   [32768][1024] bf16 @ 0          (67,108,864)
//   W1t  [2560][1024]  bf16 @ 67108864   ( 5,242,880)
//   W2t  [1280][512]   bf16 @ 72351744   ( 1,310,720)
//   t1   [32768][2560] bf16 @ 73662464   (167,772,160)
//   scr  [5][32768]    f32  @ 241434624  (    655,360)
//   lgt  [32768][5]    f32  @ 242089984  (    655,360)   total 242,745,344
// ---------------------------------------------------------------------------

typedef __bf16 bf16x8 __attribute__((ext_vector_type(8)));
typedef float f32x4 __attribute__((ext_vector_type(4)));

#define NEG_INF_VAL (-10000.0f)

__device__ __forceinline__ unsigned short f2bf(float f) {
  union { float f; unsigned u; } v; v.f = f;
  unsigned r = v.u + 0x7fffu + ((v.u >> 16) & 1u);   // RNE
  return (unsigned short)(r >> 16);
}
__device__ __forceinline__ float bf2f(unsigned short b) {
  union { unsigned u; float f; } v; v.u = ((unsigned)b) << 16;
  return v.f;
}
__device__ __forceinline__ float gelu_erf(float x) {
  return 0.5f * x * (1.0f + erff(x * 0.7071067811865476f));
}
__device__ __forceinline__ float gelu_fast(float x) {
  float u = 0.7978845608f * x * (1.0f + 0.044715f * x * x);
  float e = __expf(-2.0f * fabsf(u));
  float t = (1.0f - e) / (1.0f + e);
  t = copysignf(t, u);
  return 0.5f * x * (1.0f + t);
}

// ---- h fp32 -> bf16 ----
__global__ __launch_bounds__(256) void k_f32_to_bf16x4(
    const float* __restrict__ in, unsigned short* __restrict__ out, int n4) {
  int i = blockIdx.x * 256 + threadIdx.x;
  if (i >= n4) return;
  float4 v = reinterpret_cast<const float4*>(in)[i];
  ushort4 o;
  o.x = f2bf(v.x); o.y = f2bf(v.y); o.z = f2bf(v.z); o.w = f2bf(v.w);
  reinterpret_cast<ushort4*>(out)[i] = o;
}

// ---- tiled transpose: W [M][K][C] f32 -> Wt [M][C][K] bf16 ----
__global__ __launch_bounds__(256) void k_transpose_tiled(
    const float* __restrict__ W, unsigned short* __restrict__ Wt,
    int K, int C) {
  __shared__ float tile[32][33];
  const int m = blockIdx.z;
  const int c0 = blockIdx.x * 32, k0 = blockIdx.y * 32;
  const int tx = threadIdx.x & 31, ty = threadIdx.x >> 5;
  const float* Wm = W + (size_t)m * K * C;
#pragma unroll
  for (int r = ty; r < 32; r += 8)
    tile[r][tx] = Wm[(size_t)(k0 + r) * C + c0 + tx];
  __syncthreads();
  unsigned short* Wtm = Wt + (size_t)m * C * K;
#pragma unroll
  for (int r = ty; r < 32; r += 8)
    Wtm[(size_t)(c0 + r) * K + k0 + tx] = f2bf(tile[tx][r]);
}

// ---- stage one 256x64 K-tile of A and B (8 x global_load_lds / thread).
// Wave w stages its 16-row subtile per 128-row half; per row the 2 loads of a
// lane-pair group cover a full 128B line (chunks 0-3 then 4-7).
// LDS granule layout: subtile(2KB)= [chunk(8)][row(16)][16B]; dest = base+l*16.
__device__ __forceinline__ void stage_tile(
    const unsigned short* __restrict__ A, size_t lda,
    const unsigned short* __restrict__ B, size_t ldb,
    int rowA0, int rowB0, int k0,
    unsigned short* As, unsigned short* Bs, int w, int l) {
  const int r = l & 15;
  const int c8 = (l >> 4) * 8;
#pragma unroll
  for (int h = 0; h < 2; ++h) {
    const unsigned short* ga = A + (size_t)(rowA0 + h * 128 + w * 16 + r) * lda + k0 + c8;
    unsigned short* da = As + (h * 8 + w) * 1024 + l * 8;
    __builtin_amdgcn_global_load_lds((const __attribute__((address_space(1))) void*)ga,
                                     (__attribute__((address_space(3))) void*)da, 16, 0, 0);
    __builtin_amdgcn_global_load_lds((const __attribute__((address_space(1))) void*)(ga + 32),
                                     (__attribute__((address_space(3))) void*)(da + 512), 16, 0, 0);
    const unsigned short* gb = B + (size_t)(rowB0 + h * 128 + w * 16 + r) * ldb + k0 + c8;
    unsigned short* db = Bs + (h * 8 + w) * 1024 + l * 8;
    __builtin_amdgcn_global_load_lds((const __attribute__((address_space(1))) void*)gb,
                                     (__attribute__((address_space(3))) void*)db, 16, 0, 0);
    __builtin_amdgcn_global_load_lds((const __attribute__((address_space(1))) void*)(gb + 32),
                                     (__attribute__((address_space(3))) void*)(db + 512), 16, 0, 0);
  }
}

// ---- 256x256 GEMM; FUSE_SCORES: epilogue = gelu -> dot(W3) -> scores ----
template <bool FUSE_SCORES>
__global__ __launch_bounds__(512) void k_gemm256(
    const unsigned short* __restrict__ A, int lda, int aOffPerM,
    const unsigned short* __restrict__ Bt, int K,          // ldb == K
    const float* __restrict__ bias,
    unsigned short* __restrict__ C, int ldc,
    const float* __restrict__ W3, const float* __restrict__ b3,
    float* __restrict__ scoresOut,
    int tilesPerM, int colsPerM, int nColTiles) {
  __shared__ __align__(16) unsigned short As[2][16384];
  __shared__ __align__(16) unsigned short Bs[2][16384];
  __shared__ float sc[256];
  const int t512 = threadIdx.x;
  const int w = t512 >> 6, l = t512 & 63;
  const int wr = w >> 2, wc = w & 3;

  const int nwg = gridDim.x;
  const int cpx = nwg >> 3;
  const int bid = blockIdx.x;
  const int swz = (bid & 7) * cpx + (bid >> 3);      // bijective: nwg % 8 == 0
  const int ct = swz % nColTiles, rt = swz / nColTiles;
  const int m = ct / tilesPerM, cb = ct - m * tilesPerM;
  const int gcol0 = m * colsPerM + cb * 256;
  const int row0 = rt * 256;
  const unsigned short* Am = A + (size_t)m * aOffPerM;  // column offset < lda

  if (FUSE_SCORES && t512 < 256) sc[t512] = 0.f;

  f32x4 acc[8][4] = {};
  const int NT = K >> 6;

  stage_tile(Am, lda, Bt, K, row0, gcol0, 0, As[0], Bs[0], w, l);
  stage_tile(Am, lda, Bt, K, row0, gcol0, 64, As[1], Bs[1], w, l);
  asm volatile("s_waitcnt vmcnt(8)" ::: "memory");   // tile0 landed
  __builtin_amdgcn_sched_barrier(0);
  __builtin_amdgcn_s_barrier();
  __builtin_amdgcn_sched_barrier(0);

  for (int t = 0; t < NT; ++t) {
    const int p = t & 1;
    bf16x8 af[8][2], bf[4][2];
#pragma unroll
    for (int i = 0; i < 8; ++i)
#pragma unroll
      for (int ks = 0; ks < 2; ++ks)
        af[i][ks] = *reinterpret_cast<const bf16x8*>(&As[p][(wr * 8 + i) * 1024 + ks * 512 + l * 8]);
#pragma unroll
    for (int j = 0; j < 4; ++j)
#pragma unroll
      for (int ks = 0; ks < 2; ++ks)
        bf[j][ks] = *reinterpret_cast<const bf16x8*>(&Bs[p][(wc * 4 + j) * 1024 + ks * 512 + l * 8]);
    asm volatile("s_waitcnt lgkmcnt(0)" ::: "memory");  // my reads of slot p done
    __builtin_amdgcn_sched_barrier(0);
    __builtin_amdgcn_s_barrier();                       // everyone's reads done
    __builtin_amdgcn_sched_barrier(0);
    if (t + 2 < NT)                                     // refill freed slot
      stage_tile(Am, lda, Bt, K, row0, gcol0, (t + 2) * 64, As[p], Bs[p], w, l);
    __builtin_amdgcn_sched_barrier(0);
    __builtin_amdgcn_s_setprio(1);
#pragma unroll
    for (int ks = 0; ks < 2; ++ks)
#pragma unroll
      for (int i = 0; i < 8; ++i)
#pragma unroll
        for (int j = 0; j < 4; ++j)
          acc[i][j] = __builtin_amdgcn_mfma_f32_16x16x32_bf16(af[i][ks], bf[j][ks], acc[i][j], 0, 0, 0);
    __builtin_amdgcn_s_setprio(0);
    __builtin_amdgcn_sched_barrier(0);
    if (t + 1 < NT) {
      if (t + 2 < NT) { asm volatile("s_waitcnt vmcnt(8)" ::: "memory"); }  // t+1 landed
      else            { asm volatile("s_waitcnt vmcnt(0)" ::: "memory"); }
      __builtin_amdgcn_sched_barrier(0);
      __builtin_amdgcn_s_barrier();
      __builtin_amdgcn_sched_barrier(0);
    }
  }

  if (!FUSE_SCORES) {
    const int orow = (l >> 4) * 4, ocol = l & 15;
#pragma unroll
    for (int i = 0; i < 8; ++i)
#pragma unroll
      for (int j = 0; j < 4; ++j) {
        const int gc = gcol0 + wc * 64 + j * 16 + ocol;
        const float bv = bias[gc];
        const int gr0 = row0 + wr * 128 + i * 16 + orow;
#pragma unroll
        for (int r = 0; r < 4; ++r) {
          float v = gelu_fast(acc[i][j][r] + bv);
          C[(size_t)(gr0 + r) * ldc + gc] = f2bf(v);
        }
      }
  } else {
    const int ocol = l & 15;
#pragma unroll
    for (int i = 0; i < 8; ++i) {
      float rs[4] = {0.f, 0.f, 0.f, 0.f};
#pragma unroll
      for (int j = 0; j < 4; ++j) {
        const int cl = wc * 64 + j * 16 + ocol;        // 0..255 within marker
        const float bv = bias[m * 256 + cl];           // b2 fused [1280]
        const float w3v = W3[m * 256 + cl];
#pragma unroll
        for (int r = 0; r < 4; ++r)
          rs[r] += gelu_fast(acc[i][j][r] + bv) * w3v;
      }
#pragma unroll
      for (int s = 1; s < 16; s <<= 1)
#pragma unroll
        for (int r = 0; r < 4; ++r)
          rs[r] += __shfl_xor(rs[r], s);
      if (ocol == 0) {
        const int lr0 = wr * 128 + i * 16 + (l >> 4) * 4;
#pragma unroll
        for (int r = 0; r < 4; ++r)
          atomicAdd(&sc[lr0 + r], rs[r]);
      }
    }
    __syncthreads();
    if (t512 < 256)
      scoresOut[(size_t)m * 32768 + row0 + t512] = sc[t512] + b3[m];
  }
}

// ---- span consistency: block per (b, m) ----
__global__ __launch_bounds__(256) void k_span(
    const float* __restrict__ scores,   // [5][16][2048]
    const int* __restrict__ mask,       // [16][2048]
    const float* __restrict__ gamma,    // [5]
    const float* __restrict__ wlog,     // [5][15]
    float* __restrict__ logits) {       // [16][2048][5]
  const int b = blockIdx.x, m = blockIdx.y;
  const int tid = threadIdx.x;
  __shared__ float masked[2048], mins[2048], boost[2048];
  __shared__ float ww[14];
  if (tid == 0) {
    float mx = -1e30f;
    for (int i = 0; i < 15; i++) mx = fmaxf(mx, wlog[m * 15 + i]);
    float e[15], sum = 0.f;
    for (int i = 0; i < 15; i++) { e[i] = expf(wlog[m * 15 + i] - mx); sum += e[i]; }
    for (int i = 0; i < 14; i++) ww[i] = e[i] / sum;
  }
  const float* srow = scores + ((size_t)m * 16 + b) * 2048;
  const int* mrow = mask + (size_t)b * 2048;
  for (int i = tid; i < 2048; i += 256) {
    float s = srow[i];
    float mk = (mrow[i] == 0) ? NEG_INF_VAL : s;
    masked[i] = mk; mins[i] = mk; boost[i] = mk;
  }
  __syncthreads();
  for (int w2 = 2; w2 <= 15; w2++) {
    for (int s = tid; s <= 2048 - w2; s += 256)
      mins[s] = fminf(mins[s], masked[s + w2 - 1]);
    __syncthreads();
    float c = ww[w2 - 2];
    for (int i = tid; i < 2048; i += 256) {
      int lo = i - w2 + 1; if (lo < 0) lo = 0;
      int hi = i; if (hi > 2048 - w2) hi = 2048 - w2;
      float mx = -1e30f;
      for (int s = lo; s <= hi; s++) mx = fmaxf(mx, mins[s]);
      boost[i] = fmaxf(boost[i], mx * c);
    }
    __syncthreads();
  }
  float g = gamma[m];
  for (int i = tid; i < 2048; i += 256)
    logits[((size_t)b * 2048 + i) * 5 + m] = srow[i] + g * boost[i];
}

// ---- cross-marker refinement ----
__global__ __launch_bounds__(256) void k_cross(
    const float* __restrict__ logits, const float* __restrict__ corr,
    const float* __restrict__ cw1, const float* __restrict__ cb1,
    const float* __restrict__ cw2, const float* __restrict__ cb2,
    const float* __restrict__ gate, float* __restrict__ out) {
  __shared__ float s_corr[25], s_cw1[320], s_cb1[64], s_cw2[320], s_cb2[5];
  int tid = threadIdx.x;
  if (tid < 25) s_corr[tid] = corr[tid];
  if (tid < 64) s_cb1[tid] = cb1[tid];
  if (tid < 5)  s_cb2[tid] = cb2[tid];
  for (int i = tid; i < 320; i += 256) { s_cw1[i] = cw1[i]; s_cw2[i] = cw2[i]; }
  __syncthreads();
  int t = blockIdx.x * 256 + tid;
  float lg[5], pr[5];
#pragma unroll
  for (int m = 0; m < 5; m++) {
    lg[m] = logits[(size_t)t * 5 + m];
    pr[m] = 1.f / (1.f + expf(-lg[m]));
  }
  float co[5];
#pragma unroll
  for (int j = 0; j < 5; j++) {
    float s = 0.f;
#pragma unroll
    for (int mm = 0; mm < 5; mm++) s += pr[mm] * s_corr[mm * 5 + j];
    co[j] = s;
  }
  float ref[5];
#pragma unroll
  for (int m = 0; m < 5; m++) ref[m] = s_cb2[m];
  for (int k = 0; k < 64; k++) {
    float h = s_cb1[k];
#pragma unroll
    for (int j = 0; j < 5; j++) h += co[j] * s_cw1[j * 64 + k];
    h = gelu_erf(h);
#pragma unroll
    for (int m = 0; m < 5; m++) ref[m] += h * s_cw2[k * 5 + m];
  }
  float sg = 1.f / (1.f + expf(-gate[0]));
#pragma unroll
  for (int m = 0; m < 5; m++) out[(size_t)t * 5 + m] = lg[m] + sg * ref[m];
}

extern "C" void kernel_launch(void* const* d_in, const int* in_sizes, int n_in,
                              void* d_out, int out_size, void* d_ws, size_t ws_size,
                              hipStream_t stream) {
  const float* h     = (const float*)d_in[0];
  const int*   mask  = (const int*)d_in[1];
  const float* W1    = (const float*)d_in[2];
  const float* b1    = (const float*)d_in[3];
  const float* W2    = (const float*)d_in[4];
  const float* b2    = (const float*)d_in[5];
  const float* W3    = (const float*)d_in[6];
  const float* b3    = (const float*)d_in[7];
  const float* gamma = (const float*)d_in[8];
  const float* wlog  = (const float*)d_in[9];
  const float* corr  = (const float*)d_in[10];
  const float* cw1   = (const float*)d_in[11];
  const float* cb1   = (const float*)d_in[12];
  const float* cw2   = (const float*)d_in[13];
  const float* cb2   = (const float*)d_in[14];
  const float* gate  = (const float*)d_in[15];
  float* out = (float*)d_out;

  char* ws = (char*)d_ws;
  unsigned short* hb  = (unsigned short*)(ws);
  unsigned short* W1t = (unsigned short*)(ws + 67108864);
  unsigned short* W2t = (unsigned short*)(ws + 72351744);
  unsigned short* t1  = (unsigned short*)(ws + 73662464);
  float* scores       = (float*)(ws + 241434624);
  float* logits       = (float*)(ws + 242089984);

  k_f32_to_bf16x4<<<33554432 / 4 / 256, 256, 0, stream>>>(h, hb, 33554432 / 4);
  k_transpose_tiled<<<dim3(16, 32, 5), 256, 0, stream>>>(W1, W1t, 1024, 512);
  k_transpose_tiled<<<dim3(8, 16, 5), 256, 0, stream>>>(W2, W2t, 512, 256);

  // GEMM1: hb[32768,1024] x W1t[2560,1024]^T -> t1 (gelu). 128x10 tiles.
  k_gemm256<false><<<1280, 512, 0, stream>>>(
      hb, 1024, 0, W1t, 1024, b1, t1, 2560,
      nullptr, nullptr, nullptr, 10, 2560, 10);
  // GEMM2+scores: per m, t1[:, m*512 +: 512] x W2t_m^T -> gelu -> dot W3[m]
  k_gemm256<true><<<640, 512, 0, stream>>>(
      t1, 2560, 512, W2t, 512, b2, nullptr, 0,
      W3, b3, scores, 1, 256, 5);

  k_span<<<dim3(16, 5), 256, 0, stream>>>(scores, mask, gamma, wlog, logits);
  k_cross<<<32768 / 256, 256, 0, stream>>>(logits, corr, cw1, cb1, cw2, cb2, gate, out);
}